// Round 14
// baseline (1645.845 us; speedup 1.0000x reference)
//
#include <hip/hip_runtime.h>
#include <hip/hip_fp16.h>

#define TT 1024
#define BB 128
#define II 256
#define HH 256
#define NG 768   // 3*H

// Static scratch: x bf16, wih^T bf16, gi f16 (bias folded), packed whh words.
__device__ __align__(16) unsigned short g_xbf[(size_t)TT * BB * II];   // 67 MB
__device__ __align__(16) unsigned short g_wihB[NG * II];               // 384 KB
__device__ __align__(16) _Float16       g_gi[(size_t)TT * BB * NG];    // 201 MB
__device__ __align__(16) unsigned       g_wpk[192 * 512];              // 384 KB packed f16x2

typedef __attribute__((ext_vector_type(8)))  short    bfrag;
typedef __attribute__((ext_vector_type(4)))  float    f32x4;
typedef __attribute__((ext_vector_type(2)))  _Float16 h2t;
typedef __attribute__((ext_vector_type(32))) unsigned u32x32;

__device__ __forceinline__ unsigned short f2bf(float f) {
    unsigned u = __float_as_uint(f);
    return (unsigned short)((u + 0x7fffu + ((u >> 16) & 1u)) >> 16);   // RNE
}
__device__ __forceinline__ unsigned pk2(float a, float b) {
    return __builtin_bit_cast(unsigned, __builtin_amdgcn_cvt_pkrtz(a, b));
}

// ---------------- phase 1a: x f32 -> bf16 ----------------
__global__ void cvt_x_kernel(const float* __restrict__ x) {
    const int n4 = TT * BB * II / 4;
    for (int i = blockIdx.x * blockDim.x + threadIdx.x; i < n4;
         i += gridDim.x * blockDim.x) {
        float4 v = reinterpret_cast<const float4*>(x)[i];
        ushort4 o;
        o.x = f2bf(v.x); o.y = f2bf(v.y); o.z = f2bf(v.z); o.w = f2bf(v.w);
        reinterpret_cast<ushort4*>(g_xbf)[i] = o;
    }
}

// ---------------- phase 1b: wihT [k][n] -> wihB [n][k] bf16 ----------------
__global__ void cvt_wih_kernel(const float* __restrict__ wihT) {
    const int n = blockIdx.x;
    const int k = threadIdx.x;
    g_wihB[n * II + k] = f2bf(wihT[k * NG + n]);
}

// ---------------- phase 1c: pack whh into per-thread word lists ----------------
// Thread t = kh*256+j of the rec kernel owns k-pairs p = kh*64+pl (pl<64),
// gate-interleaved words wt = 3*pl + gate, col = gate*256+j.
//   wt in [0,96):    REG region,    layout [wt][t]          (init loads)
//   wt in [96,174):  LDS region,    layout [quad][t][4words] (b128 reads)
//   wt in [174,192): STREAM region, layout [t][18]           (imm-offset loads)
__global__ void pack_whh_kernel(const float* __restrict__ whhT) {
    const int wt = blockIdx.x;   // 0..191
    const int t  = threadIdx.x;  // 0..511
    const int kh = t >> 8, j = t & 255;
    const int pl = wt / 3, gate = wt % 3;
    const int p  = kh * 64 + pl;
    const int c  = gate * HH + j;
    const unsigned val = pk2(whhT[(size_t)(2 * p) * NG + c],
                             whhT[(size_t)(2 * p + 1) * NG + c]);
    size_t addr;
    if (wt < 96) {
        addr = (size_t)wt * 512 + t;
    } else if (wt < 174) {
        const int lw = wt - 96;
        if (lw < 76) addr = 96 * 512 + (size_t)(lw >> 2) * 2048 + t * 4 + (lw & 3);
        else         addr = 96 * 512 + 76 * 512 + t * 2 + (lw - 76);
    } else {
        addr = 174 * 512 + (size_t)t * 18 + (wt - 174);
    }
    g_wpk[addr] = val;
}

// ---------------- phase 2: gi = x @ wihT + bias (MFMA bf16, f16 out) ----------------
__global__ void __launch_bounds__(256) gi_gemm_kernel(const float* __restrict__ bias) {
    __shared__ unsigned short Ab[128 * 32];
    __shared__ unsigned short Bb[128 * 32];
    const int tid = threadIdx.x;
    const int mt = blockIdx.x / 6, nt = blockIdx.x % 6;
    const int m0 = mt * 128, n0 = nt * 128;
    const int l = tid & 63, w = tid >> 6;
    const int wr = w >> 1, wc = w & 1;
    const int srow = tid >> 2, scol = (tid & 3) * 8;

    f32x4 acc[4][4] = {};

    for (int ks = 0; ks < 8; ++ks) {
        const int k0 = ks * 32;
        __syncthreads();
        #pragma unroll
        for (int c = 0; c < 2; ++c) {
            const int row = c * 64 + srow;
            *reinterpret_cast<uint4*>(&Ab[row * 32 + scol]) =
                *reinterpret_cast<const uint4*>(&g_xbf[(size_t)(m0 + row) * II + k0 + scol]);
            *reinterpret_cast<uint4*>(&Bb[row * 32 + scol]) =
                *reinterpret_cast<const uint4*>(&g_wihB[(n0 + row) * II + k0 + scol]);
        }
        __syncthreads();
        bfrag af[4], bf[4];
        #pragma unroll
        for (int i = 0; i < 4; ++i) {
            af[i] = *reinterpret_cast<const bfrag*>(
                        &Ab[(wr * 64 + i * 16 + (l & 15)) * 32 + (l >> 4) * 8]);
            bf[i] = *reinterpret_cast<const bfrag*>(
                        &Bb[(wc * 64 + i * 16 + (l & 15)) * 32 + (l >> 4) * 8]);
        }
        #pragma unroll
        for (int mi = 0; mi < 4; ++mi)
            #pragma unroll
            for (int ni = 0; ni < 4; ++ni)
                acc[mi][ni] = __builtin_amdgcn_mfma_f32_16x16x32_bf16(
                                  af[mi], bf[ni], acc[mi][ni], 0, 0, 0);
    }
    #pragma unroll
    for (int mi = 0; mi < 4; ++mi) {
        const int grow = m0 + wr * 64 + mi * 16 + (l >> 4) * 4;
        #pragma unroll
        for (int ni = 0; ni < 4; ++ni) {
            const int gcol = n0 + wc * 64 + ni * 16 + (l & 15);
            const float bv = bias[gcol];
            #pragma unroll
            for (int q = 0; q < 4; ++q)
                g_gi[(size_t)(grow + q) * NG + gcol] = (_Float16)(acc[mi][ni][q] + bv);
        }
    }
}

// ---------------- phase 3: recurrence, whh split reg/LDS/stream ----------------
// r2-r13 law: the RA budgets registers for 2 WGs/CU no matter what (512thr ->
// 128 regs/lane). So the 384 KB whh is tiered to fit: 96 words/thread in regs
// (196 KB), 78 words/thread in LDS (159.7 KB, staged once), 18 words/thread
// re-read each step from a 36 KB L2-hot region (same bytes for all 128 WGs).
// fdot2 datapath identical to the passing r6; gi has bias pre-folded.
#define FD(HH2, W, ACC) \
    ACC = __builtin_amdgcn_fdot2((HH2), __builtin_bit_cast(h2t, (unsigned)(W)), (ACC), false)

#define WGET(W) ((W) < 32 ? wv0[(W) & 31] : (W) < 64 ? wv1[(W) & 31] : wv2[(W) & 31])

// read h pairs PL, PL+1 (PL even) for this thread's k-half
#define HREAD(PL)                                                             \
    { const uint2 hb = *reinterpret_cast<const uint2*>(                       \
          reinterpret_cast<const _Float16*>(hbuf) + kh * 128 + (PL) * 2);     \
      hx = hb.x; hy = hb.y; }

#define DOT3(HW, W0, W1, W2)                                                  \
    { const h2t hh = __builtin_bit_cast(h2t, (unsigned)(HW));                 \
      FD(hh, W0, aR); FD(hh, W1, aZ); FD(hh, W2, aN); }

#define DREG(PL, HW) DOT3(HW, WGET(3*(PL)), WGET(3*(PL)+1), WGET(3*(PL)+2))
#define R2(PL) HREAD(PL) DREG(PL, hx) DREG((PL)+1, hy)

#define LQ(Q) (*reinterpret_cast<const uint4*>(&ldsw[(Q) * 2048 + t * 4]))

#define LBLK(PB)                                                              \
    { const uint4 q0 = LQ(3*(PB)); const uint4 q1 = LQ(3*(PB)+1);             \
      const uint4 q2 = LQ(3*(PB)+2);                                          \
      HREAD(32 + 4*(PB))                                                      \
      DOT3(hx, q0.x, q0.y, q0.z)  DOT3(hy, q0.w, q1.x, q1.y)                  \
      HREAD(34 + 4*(PB))                                                      \
      DOT3(hx, q1.z, q1.w, q2.x)  DOT3(hy, q2.y, q2.z, q2.w) }

__global__ void __launch_bounds__(512) gru_rec_kernel(
    const float* __restrict__ h0, float* __restrict__ out)
{
    __shared__ __align__(16) unsigned ldsw[78 * 512];   // 159.7 KB weights
    __shared__ float    part[3][256];                   // kh=1 partials (3 KB)
    __shared__ _Float16 hbuf[256];                      // h, single buffer

    const int t  = threadIdx.x;
    const int b  = blockIdx.x;
    const int kh = t >> 8;              // wave-uniform k-half
    const int j  = t & 255;

    // --- REG weights: 96 words (pairs 0..31), 3 x u32x32 ---
    u32x32 wv0, wv1, wv2;
    #pragma unroll
    for (int e = 0; e < 32; ++e) {
        wv0[e] = g_wpk[(size_t)(e)      * 512 + t];
        wv1[e] = g_wpk[(size_t)(32 + e) * 512 + t];
        wv2[e] = g_wpk[(size_t)(64 + e) * 512 + t];
    }

    // --- LDS weights: stage 78*512 dwords (flat copy, same layout) ---
    {
        uint4* lq = reinterpret_cast<uint4*>(ldsw);
        const uint4* gq = reinterpret_cast<const uint4*>(g_wpk + 96 * 512);
        for (int i = t; i < 78 * 512 / 4; i += 512) lq[i] = gq[i];
    }

    float hprev = h0[b * HH + j];
    if (t < 256) hbuf[t] = (_Float16)h0[b * HH + t];
    __syncthreads();

    const unsigned* sbase = g_wpk + 174 * 512 + (size_t)t * 18;

    for (int ts = 0; ts < TT; ++ts) {
        // stream weights (18 dwords, imm offsets, L2-hot) + gi (kh==0 only)
        unsigned s0 = sbase[0],  s1 = sbase[1],  s2 = sbase[2],  s3 = sbase[3];
        unsigned s4 = sbase[4],  s5 = sbase[5],  s6 = sbase[6],  s7 = sbase[7];
        unsigned s8 = sbase[8],  s9 = sbase[9],  s10 = sbase[10], s11 = sbase[11];
        unsigned s12 = sbase[12], s13 = sbase[13], s14 = sbase[14], s15 = sbase[15];
        unsigned s16 = sbase[16], s17 = sbase[17];
        float giR = 0.f, giZ = 0.f, giN = 0.f;
        if (kh == 0) {
            const _Float16* gb = g_gi + ((size_t)ts * BB + b) * NG + j;
            giR = (float)gb[0]; giZ = (float)gb[256]; giN = (float)gb[512];
        }

        float aR = 0.f, aZ = 0.f, aN = 0.f;
        unsigned hx, hy;

        // REG phase: pairs 0..31 (covers the stream-load latency)
        R2(0)  R2(2)  R2(4)  R2(6)  R2(8)  R2(10) R2(12) R2(14)
        R2(16) R2(18) R2(20) R2(22) R2(24) R2(26) R2(28) R2(30)

        // STREAM phase: pairs 58..63 (consume early to cap liveness)
        HREAD(58) DOT3(hx, s0, s1, s2)    DOT3(hy, s3, s4, s5)
        HREAD(60) DOT3(hx, s6, s7, s8)    DOT3(hy, s9, s10, s11)
        HREAD(62) DOT3(hx, s12, s13, s14) DOT3(hy, s15, s16, s17)

        // LDS phase: pairs 32..57 (6 blocks of 4 pairs + 2-pair tail)
        LBLK(0) LBLK(1) LBLK(2) LBLK(3) LBLK(4) LBLK(5)
        {   // tail: pairs 56,57 = quad 18 + b64
            const uint4 q = LQ(18);
            const uint2 b2 = *reinterpret_cast<const uint2*>(&ldsw[76 * 512 + t * 2]);
            HREAD(56)
            DOT3(hx, q.x, q.y, q.z)
            DOT3(hy, q.w, b2.x, b2.y)
        }

        // combine k-halves + epilogue
        if (kh == 1) {
            part[0][j] = aR; part[1][j] = aZ; part[2][j] = aN;
        }
        __syncthreads();
        if (kh == 0) {
            const float sR = aR + part[0][j];
            const float sZ = aZ + part[1][j];
            const float sN = aN + part[2][j];
            const float r = 1.f / (1.f + __expf(-(sR + giR)));
            const float z = 1.f / (1.f + __expf(-(sZ + giZ)));
            const float e = __expf(2.f * (giN + r * sN));   // tanh
            const float n = 1.f - 2.f / (e + 1.f);
            const float hv = (1.f - z) * n + z * hprev;
            hprev = hv;
            hbuf[j] = (_Float16)hv;                 // safe: all reads pre-barrier
            if (ts == TT - 1) out[b * HH + j] = hv;
        }
        __syncthreads();
    }
}

extern "C" void kernel_launch(void* const* d_in, const int* in_sizes, int n_in,
                              void* d_out, int out_size, void* d_ws, size_t ws_size,
                              hipStream_t stream) {
    const float* x    = (const float*)d_in[0];
    const float* h0   = (const float*)d_in[1];
    const float* wihT = (const float*)d_in[2];
    const float* whhT = (const float*)d_in[3];
    const float* bias = (const float*)d_in[4];
    float*       out  = (float*)d_out;

    cvt_x_kernel<<<2048, 256, 0, stream>>>(x);
    cvt_wih_kernel<<<NG, 256, 0, stream>>>(wihT);
    pack_whh_kernel<<<192, 512, 0, stream>>>(whhT);
    gi_gemm_kernel<<<1024 * 6, 256, 0, stream>>>(bias);
    gru_rec_kernel<<<BB, 512, 0, stream>>>(h0, out);
}